// Round 1
// baseline (293.113 us; speedup 1.0000x reference)
//
#include <hip/hip_runtime.h>
#include <math.h>

#define D_MODEL 1024
#define T_SEQ   2048
#define NBATCH  4
#define NROWS   (NBATCH * T_SEQ)          // 8192
#define NOUT    64                        // 32 q + 32 k
#define NQTR    4                         // s-quarters in sim

#define SKLD 264   // klds row stride (floats): 256 + 8, 16B aligned, <=2-way banks
#define SQLD 36    // qlds row stride (floats): 32 + 4
#define XLD  1032  // xlds row stride (floats): 1024 + 8, 16B aligned

typedef double v4df __attribute__((ext_vector_type(4)));

// ---------- top-4 helpers: total order = (value desc, index asc) ----------
__device__ __forceinline__ bool key_gt(float av, int ai, float bv, int bi) {
    return (av > bv) || (av == bv && ai < bi);
}

__device__ __forceinline__ void cmpswap(float& v0, int& i0, float& v1, int& i1) {
    bool sw = key_gt(v1, i1, v0, i0);
    float nv0 = sw ? v1 : v0, nv1 = sw ? v0 : v1;
    int   ni0 = sw ? i1 : i0, ni1 = sw ? i0 : i1;
    v0 = nv0; v1 = nv1; i0 = ni0; i1 = ni1;
}

// merge sorted-desc a[4] with sorted-desc b[4] -> top4 of union into a (bitonic)
__device__ __forceinline__ void merge4(float (&a)[4], int (&ai)[4],
                                       float b0, int j0, float b1, int j1,
                                       float b2, int j2, float b3, int j3) {
    if (!key_gt(a[0], ai[0], b3, j3)) { a[0] = b3; ai[0] = j3; }
    if (!key_gt(a[1], ai[1], b2, j2)) { a[1] = b2; ai[1] = j2; }
    if (!key_gt(a[2], ai[2], b1, j1)) { a[2] = b1; ai[2] = j1; }
    if (!key_gt(a[3], ai[3], b0, j0)) { a[3] = b0; ai[3] = j0; }
    cmpswap(a[0], ai[0], a[2], ai[2]);
    cmpswap(a[1], ai[1], a[3], ai[3]);
    cmpswap(a[0], ai[0], a[1], ai[1]);
    cmpswap(a[2], ai[2], a[3], ai[3]);
}

// insert candidate (v, idx) into sorted-desc top4; strict > keeps earlier index on ties
__device__ __forceinline__ void insert4(float (&tv)[4], int (&tix)[4], float v, int idx) {
    if (v > tv[3]) {
        bool g0 = v > tv[0], g1 = v > tv[1], g2 = v > tv[2];
        float n0 = g0 ? v : tv[0];
        int   m0 = g0 ? idx : tix[0];
        float n1 = g1 ? (g0 ? tv[0] : v) : tv[1];
        int   m1 = g1 ? (g0 ? tix[0] : idx) : tix[1];
        float n2 = g2 ? (g1 ? tv[1] : v) : tv[2];
        int   m2 = g2 ? (g1 ? tix[1] : idx) : tix[2];
        float n3 = g2 ? tv[2] : v;
        int   m3 = g2 ? tix[2] : idx;
        tv[0] = n0; tv[1] = n1; tv[2] = n2; tv[3] = n3;
        tix[0] = m0; tix[1] = m1; tix[2] = m2; tix[3] = m3;
    }
}

// ---------- probe body: f64 MFMA fragment layout, run by one 256-thr block ----------
// tab layout (ints): [0]=flag, [1..64]=am, [65..128]=ak, [129..192]=bk,
//                    [193..256]=bn, [257..512]=dm[lane][4], [513..768]=dn[lane][4]
__device__ void run_probe(int tid, int* __restrict__ tab)
{
    __shared__ double Aref[16][4];
    __shared__ double Bref[4][16];
    __shared__ double Dref[16][16];

    const int lane = tid;   // only tid<64 used for lane-specific work
    if (tid < 64) {
        const int m = lane & 15, k = lane >> 4;
        Aref[m][k] = (double)(1 + m * 4 + k);     // distinct, asymmetric
        Bref[k][m] = (double)(1 + k * 16 + m);
    }
    __syncthreads();
    {   // 256 threads: one D element each
        const int e = tid;
        const int m = e >> 4, n = e & 15;
        double s = 0.0;
        for (int k = 0; k < 4; ++k) s += Aref[m][k] * Bref[k][n];
        Dref[m][n] = s;   // exact integer-valued f64
    }
    __syncthreads();

    if (tid >= 64) return;   // wave 0 does the hypothesis search

    int found = -1;
    for (int h = 0; h < 16; ++h) {
        if (found >= 0) break;
        const int fa = h & 1, fb = (h >> 1) & 1, fd = h >> 2;
        const int am = fa ? (lane >> 2) : (lane & 15);
        const int ak = fa ? (lane & 3)  : (lane >> 4);
        const int bn = fb ? (lane >> 2) : (lane & 15);
        const int bk = fb ? (lane & 3)  : (lane >> 4);
        v4df c = {0.0, 0.0, 0.0, 0.0};
        c = __builtin_amdgcn_mfma_f64_16x16x4f64(Aref[am][ak], Bref[bk][bn], c, 0, 0, 0);
        bool ok = true;
        #pragma unroll
        for (int i = 0; i < 4; ++i) {
            int dm, dn;
            if (fd == 0)      { dm = 4 * (lane >> 4) + i; dn = lane & 15; }
            else if (fd == 1) { dn = 4 * (lane >> 4) + i; dm = lane & 15; }
            else if (fd == 2) { dm = (lane >> 4) + 4 * i; dn = lane & 15; }
            else              { dn = (lane >> 4) + 4 * i; dm = lane & 15; }
            if (c[i] != Dref[dm][dn]) ok = false;
        }
        if (__all(ok)) found = h;
    }

    const int fa = (found >= 0) ? (found & 1) : 0;
    const int fb = (found >= 0) ? ((found >> 1) & 1) : 0;
    const int fd = (found >= 0) ? (found >> 2) : 0;
    tab[1   + lane] = fa ? (lane >> 2) : (lane & 15);
    tab[65  + lane] = fa ? (lane & 3)  : (lane >> 4);
    tab[129 + lane] = fb ? (lane & 3)  : (lane >> 4);
    tab[193 + lane] = fb ? (lane >> 2) : (lane & 15);
    #pragma unroll
    for (int i = 0; i < 4; ++i) {
        int dm, dn;
        if (fd == 0)      { dm = 4 * (lane >> 4) + i; dn = lane & 15; }
        else if (fd == 1) { dn = 4 * (lane >> 4) + i; dm = lane & 15; }
        else if (fd == 2) { dm = (lane >> 4) + 4 * i; dn = lane & 15; }
        else              { dn = (lane >> 4) + 4 * i; dm = lane & 15; }
        tab[257 + lane * 4 + i] = dm;
        tab[513 + lane * 4 + i] = dn;
    }
    if (lane == 0) tab[0] = found;
}

// ---------- Phase 1: W convert (all blocks) + probe (block 0) + cnt zero (block 1) ----------
__global__ __launch_bounds__(256) void wprep_probe(
    const float* __restrict__ Wq, const float* __restrict__ Wk,
    double* __restrict__ Wdt, int* __restrict__ tab, int* __restrict__ cnt)
{
    const int tid = threadIdx.x;
    const int idx = blockIdx.x * 256 + tid;   // 65536 total
    const int o = idx & 63;
    const int d = idx >> 6;
    float v = (o < 32) ? Wq[(size_t)o * D_MODEL + d]
                       : Wk[(size_t)(o - 32) * D_MODEL + d];
    Wdt[(size_t)d * 64 + o] = (double)v;

    if (blockIdx.x == 1) cnt[tid] = 0;        // 256 completion counters (4 b x 64 tt)
    if (blockIdx.x == 0) run_probe(tid, tab); // full-block barriers inside
}

// ---------- Phase 2: projection via f64 MFMA, d-split wave pairs ----------
// grid 512 (= 8192 rows / 16), block 512 (8 waves). Wave pair (og, half):
// og = wav>>1 owns out-tile og*16; half = wav&1 owns d in [half*512, half*512+512).
// x staged once (16 rows x 1024 d, 66 KB); f64 combine low+high fixed order.
__global__ __launch_bounds__(512) void proj_mfma(
    const float* __restrict__ x, const double* __restrict__ Wdt,
    const float* __restrict__ bq, const float* __restrict__ bk_,
    const int* __restrict__ tab,
    float* __restrict__ Qt, float* __restrict__ Kt)
{
    __shared__ float  xlds[16 * XLD];     // 66048 B
    __shared__ double comb[4][64][4];     // 8192 B

    const int tid  = threadIdx.x;
    const int lane = tid & 63;
    const int wav  = tid >> 6;                                      // 0..7
    const int og   = __builtin_amdgcn_readfirstlane(wav >> 1);      // 0..3
    const int half = __builtin_amdgcn_readfirstlane(wav & 1);       // 0..1
    const int row0 = blockIdx.x * 16;
    const int dbase = half * 512;

    const int flag = tab[0];
    const int am  = tab[1   + lane];
    const int ak  = tab[65  + lane];
    const int bkk = tab[129 + lane];
    const int bn  = tab[193 + lane];

    const double* wcol = Wdt + og * 16;   // + d*64 + bn

    // stage x: 16 rows x 1024 d = 4096 float4, 8 per thread, coalesced
    #pragma unroll
    for (int j = 0; j < 8; ++j) {
        const int f  = j * 512 + tid;
        const int r  = f >> 8;            // 0..15
        const int c4 = f & 255;           // float4 within row
        float4 v = *reinterpret_cast<const float4*>(
            x + (size_t)(row0 + r) * D_MODEL + c4 * 4);
        *reinterpret_cast<float4*>(&xlds[r * XLD + c4 * 4]) = v;
    }
    __syncthreads();

    v4df acc = {0.0, 0.0, 0.0, 0.0};

    if (flag >= 0) {
        // 128 chained MFMAs over this half's 512 d (k ascending, deterministic)
        #pragma unroll 8
        for (int kk = 0; kk < 128; ++kk) {
            double a = (double)xlds[am * XLD + dbase + kk * 4 + ak];
            double b = wcol[(size_t)(dbase + kk * 4 + bkk) * 64 + bn];
            acc = __builtin_amdgcn_mfma_f64_16x16x4f64(a, b, acc, 0, 0, 0);
        }
    } else {
        // scalar f64 fallback: out n = lane&15, rows 4*(lane>>4)+i
        const int n  = lane & 15;
        const int r4 = (lane >> 4) * 4;
        for (int dd = 0; dd < 512; ++dd) {
            const int d = dbase + dd;
            double wv = wcol[(size_t)d * 64 + n];
            #pragma unroll
            for (int i = 0; i < 4; ++i)
                acc[i] = fma((double)xlds[(r4 + i) * XLD + d], wv, acc[i]);
        }
    }

    if (half == 1) {
        #pragma unroll
        for (int i = 0; i < 4; ++i) comb[og][lane][i] = acc[i];
    }
    __syncthreads();

    if (half == 0) {
        // total = low + high (fixed order -> deterministic), + bias, store
        #pragma unroll
        for (int i = 0; i < 4; ++i) {
            const double tot = acc[i] + comb[og][lane][i];
            const int dmv = tab[257 + lane * 4 + i];
            const int dnv = tab[513 + lane * 4 + i];
            const int out = og * 16 + dnv;
            const int row = row0 + dmv;
            const int bb  = row >> 11, t = row & 2047;
            const double bias = (out < 32) ? (double)bq[out] : (double)bk_[out - 32];
            const float v = (float)(tot + bias);
            if (out < 32) Qt[((size_t)bb * 32 + out) * T_SEQ + t] = v;
            else          Kt[((size_t)bb * 32 + (out - 32)) * T_SEQ + t] = v;
        }
    }
}

// ---------- Phase 3: sim + per-row top-4 + fused merge/gather (last quarter wins) ----------
// grid 1024 = b(4) x ttile(64) x quarter(4); block 256 (4 waves)
// tile: 32 t-rows x 512 s (2 stages of 256). micro-tile 4t x 8s.
// cV/cI/topIdx aliased into klds (dead after FMA loop) -> 38.4 KB LDS -> 4 blocks/CU.
// Completion protocol: write quarter candidates -> threadfence -> atomicAdd; the
// block observing old==3 merges all 4 quarters and gathers its 32 rows. No waiting,
// no dispatch-order assumption; counters zeroed by wprep_probe earlier in stream.
__global__ __launch_bounds__(256, 4) void sim_topk_gather(
    const float* __restrict__ x,
    const float* __restrict__ Qt, const float* __restrict__ Kt,
    float* __restrict__ candVal /* [NQTR][NROWS][4] */,
    int*   __restrict__ candIdx /* [NQTR][NROWS][4] */,
    int*   __restrict__ cnt     /* [NBATCH*64] */,
    float* __restrict__ out)
{
    __shared__ float klds[32 * SKLD];     // 33792 B
    __shared__ float qlds[32 * SQLD];     // 4608 B
    // aliases into klds, used only after the FMA loop (barrier-protected)
    float (*cV)[32][4] = reinterpret_cast<float(*)[32][4]>(klds);          // 2048 B
    int   (*cI)[32][4] = reinterpret_cast<int(*)[32][4]>(klds + 512);      // 2048 B
    int   (*topIdx)[4] = reinterpret_cast<int(*)[4]>(klds + 1024);         // 512 B
    int*   lastFlag    = reinterpret_cast<int*>(klds + 1152);

    const int tid  = threadIdx.x;
    const int lane = tid & 63;
    const int wav  = tid >> 6;            // 0..3
    const int qtr  = blockIdx.x & 3;
    const int tt   = (blockIdx.x >> 2) & 63;
    const int b    = blockIdx.x >> 8;
    const int tblk = tt * 32;
    const int sq0  = qtr * 512;

    const float* QtB = Qt + (size_t)b * 32 * T_SEQ;
    const float* KtB = Kt + (size_t)b * 32 * T_SEQ;

    // stage Q^T tile: 32 i x 32 t (exactly 256 float4s)
    {
        const int i  = tid >> 3;
        const int t4 = (tid & 7) * 4;
        float4 v = *reinterpret_cast<const float4*>(QtB + (size_t)i * T_SEQ + tblk + t4);
        *reinterpret_cast<float4*>(&qlds[i * SQLD + t4]) = v;
    }

    const int t0 = (tid & 7) * 4;         // 8 t-groups x 4 rows
    const int s0 = (tid >> 3) * 8;        // 32 s-groups x 8

    float tv[4][4]; int tix[4][4];
    #pragma unroll
    for (int r = 0; r < 4; ++r)
        #pragma unroll
        for (int j = 0; j < 4; ++j) { tv[r][j] = -INFINITY; tix[r][j] = 0x7fffffff; }

    for (int st = 0; st < 2; ++st) {
        __syncthreads();   // covers qlds at st==0, prev klds consumption after
        // stage K^T tile: 32 i x 256 s (2048 float4s, 8/thread), coalesced
        #pragma unroll
        for (int j = 0; j < 8; ++j) {
            const int f  = (tid + j * 256) * 4;
            const int ki = f >> 8;
            const int ks = f & 255;
            float4 v = *reinterpret_cast<const float4*>(
                KtB + (size_t)ki * T_SEQ + sq0 + st * 256 + ks);
            *reinterpret_cast<float4*>(&klds[ki * SKLD + ks]) = v;
        }
        __syncthreads();

        float acc[4][8];
        #pragma unroll
        for (int r = 0; r < 4; ++r)
            #pragma unroll
            for (int c = 0; c < 8; ++c) acc[r][c] = 0.f;

        #pragma unroll 4
        for (int i = 0; i < 32; ++i) {
            float4 qv  = *reinterpret_cast<const float4*>(&qlds[i * SQLD + t0]);
            float4 kv0 = *reinterpret_cast<const float4*>(&klds[i * SKLD + s0]);
            float4 kv1 = *reinterpret_cast<const float4*>(&klds[i * SKLD + s0 + 4]);
            const float qa[4] = {qv.x, qv.y, qv.z, qv.w};
            const float ka[8] = {kv0.x, kv0.y, kv0.z, kv0.w, kv1.x, kv1.y, kv1.z, kv1.w};
            #pragma unroll
            for (int r = 0; r < 4; ++r)
                #pragma unroll
                for (int c = 0; c < 8; ++c)
                    acc[r][c] = fmaf(qa[r], ka[c], acc[r][c]);
        }

        const int sbase = sq0 + st * 256 + s0;
        #pragma unroll
        for (int c = 0; c < 8; ++c)
            #pragma unroll
            for (int r = 0; r < 4; ++r)
                insert4(tv[r], tix[r], acc[r][c], sbase + c);
    }

    // wave butterfly: masks 8..32 preserve t-group (lane&7)
    #pragma unroll
    for (int m = 8; m <= 32; m <<= 1) {
        #pragma unroll
        for (int r = 0; r < 4; ++r) {
            float b0 = __shfl_xor(tv[r][0], m, 64);
            float b1 = __shfl_xor(tv[r][1], m, 64);
            float b2 = __shfl_xor(tv[r][2], m, 64);
            float b3 = __shfl_xor(tv[r][3], m, 64);
            int   j0 = __shfl_xor(tix[r][0], m, 64);
            int   j1 = __shfl_xor(tix[r][1], m, 64);
            int   j2 = __shfl_xor(tix[r][2], m, 64);
            int   j3 = __shfl_xor(tix[r][3], m, 64);
            merge4(tv[r], tix[r], b0, j0, b1, j1, b2, j2, b3, j3);
        }
    }

    __syncthreads();   // klds dead everywhere before aliased cV/cI writes

    if (lane < 8) {
        #pragma unroll
        for (int r = 0; r < 4; ++r)
            #pragma unroll
            for (int j = 0; j < 4; ++j) {
                cV[wav][lane * 4 + r][j] = tv[r][j];
                cI[wav][lane * 4 + r][j] = tix[r][j];
            }
    }
    __syncthreads();

    // cross-wave merge (4 waves), write per-quarter candidate lists
    if (tid < 32) {
        float mv[4]; int mi[4];
        #pragma unroll
        for (int j = 0; j < 4; ++j) { mv[j] = cV[0][tid][j]; mi[j] = cI[0][tid][j]; }
        #pragma unroll
        for (int w = 1; w < 4; ++w)
            merge4(mv, mi,
                   cV[w][tid][0], cI[w][tid][0],
                   cV[w][tid][1], cI[w][tid][1],
                   cV[w][tid][2], cI[w][tid][2],
                   cV[w][tid][3], cI[w][tid][3]);
        const size_t row = (size_t)b * T_SEQ + tblk + tid;
        float4 vv = {mv[0], mv[1], mv[2], mv[3]};
        int4   ii = {mi[0], mi[1], mi[2], mi[3]};
        *reinterpret_cast<float4*>(candVal + ((size_t)qtr * NROWS + row) * 4) = vv;
        *reinterpret_cast<int4*>(candIdx + ((size_t)qtr * NROWS + row) * 4) = ii;
    }

    // ---- completion protocol: last of 4 quarter-blocks merges + gathers ----
    __threadfence();                       // release: each thread's stores device-visible
    __syncthreads();                       // all fences done before the atomic
    if (tid == 0) {
        int old = atomicAdd(cnt + ((b << 6) | tt), 1);
        *lastFlag = (old == 3);
    }
    __syncthreads();
    if (!*lastFlag) return;
    __threadfence();                       // acquire: see other quarters' candidates

    if (tid < 32) {
        const size_t row = (size_t)b * T_SEQ + tblk + tid;
        float4 v0 = *reinterpret_cast<const float4*>(candVal + row * 4);
        int4   i0 = *reinterpret_cast<const int4*>(candIdx + row * 4);
        float mv[4] = {v0.x, v0.y, v0.z, v0.w};
        int   mi[4] = {i0.x, i0.y, i0.z, i0.w};
        #pragma unroll
        for (int q = 1; q < NQTR; ++q) {
            float4 v1 = *reinterpret_cast<const float4*>(candVal + ((size_t)q * NROWS + row) * 4);
            int4   i1 = *reinterpret_cast<const int4*>(candIdx + ((size_t)q * NROWS + row) * 4);
            merge4(mv, mi, v1.x, i1.x, v1.y, i1.y, v1.z, i1.z, v1.w, i1.w);
        }
        #pragma unroll
        for (int j = 0; j < 4; ++j) topIdx[tid][j] = mi[j];
    }
    __syncthreads();

    // gather + mean for this block's 32 rows; 256 threads cover the 1024-float row
    const float* xb = x + (size_t)b * T_SEQ * D_MODEL;
    float* ob = out + ((size_t)b * T_SEQ + tblk) * D_MODEL;
    #pragma unroll 4
    for (int r = 0; r < 32; ++r) {
        const int i0 = topIdx[r][0], i1 = topIdx[r][1], i2 = topIdx[r][2], i3 = topIdx[r][3];
        float4 a0 = *(reinterpret_cast<const float4*>(xb + (size_t)i0 * D_MODEL) + tid);
        float4 a1 = *(reinterpret_cast<const float4*>(xb + (size_t)i1 * D_MODEL) + tid);
        float4 a2 = *(reinterpret_cast<const float4*>(xb + (size_t)i2 * D_MODEL) + tid);
        float4 a3 = *(reinterpret_cast<const float4*>(xb + (size_t)i3 * D_MODEL) + tid);
        float4 o;
        o.x = (a0.x + a1.x + a2.x + a3.x) * 0.25f;
        o.y = (a0.y + a1.y + a2.y + a3.y) * 0.25f;
        o.z = (a0.z + a1.z + a2.z + a3.z) * 0.25f;
        o.w = (a0.w + a1.w + a2.w + a3.w) * 0.25f;
        *(reinterpret_cast<float4*>(ob + (size_t)r * D_MODEL) + tid) = o;
    }
}

extern "C" void kernel_launch(void* const* d_in, const int* in_sizes, int n_in,
                              void* d_out, int out_size, void* d_ws, size_t ws_size,
                              hipStream_t stream) {
    const float* x  = (const float*)d_in[0];
    const float* Wq = (const float*)d_in[1];
    const float* bq = (const float*)d_in[2];
    const float* Wk = (const float*)d_in[3];
    const float* bk = (const float*)d_in[4];
    float* out = (float*)d_out;

    // ws layout: [tab 4KB][Wdt 512KB][Qt 1MB][Kt 1MB][candVal 512KB][candIdx 512KB][cnt 1KB]
    char* wsb = (char*)d_ws;
    int*    tab  = (int*)wsb;                                            // 4 KB reserved
    double* Wdt  = (double*)(wsb + 4096);                                // 512 KB
    float*  Qt   = (float*)(wsb + 4096 + (size_t)D_MODEL * NOUT * 8);    // 1 MB
    float*  Kt   = Qt + (size_t)NBATCH * 32 * T_SEQ;                     // 1 MB
    float*  candVal = (float*)((char*)Kt + (size_t)NBATCH * 32 * T_SEQ * 4);
    int*    candIdx = (int*)((char*)candVal + (size_t)NQTR * NROWS * 4 * 4);
    int*    cnt     = (int*)((char*)candIdx + (size_t)NQTR * NROWS * 4 * 4);

    wprep_probe<<<dim3(256), dim3(256), 0, stream>>>(Wq, Wk, Wdt, tab, cnt);
    proj_mfma<<<dim3(NROWS / 16), dim3(512), 0, stream>>>(x, Wdt, bq, bk, tab, Qt, Kt);
    sim_topk_gather<<<dim3(1024), dim3(256), 0, stream>>>(x, Qt, Kt, candVal, candIdx, cnt, out);
}

// Round 2
// 162.256 us; speedup vs baseline: 1.8065x; 1.8065x over previous
//
#include <hip/hip_runtime.h>
#include <math.h>

#define D_MODEL 1024
#define T_SEQ   2048
#define NBATCH  4
#define NROWS   (NBATCH * T_SEQ)          // 8192
#define NOUT    64                        // 32 q + 32 k

#define SKLD 520   // klds row stride (floats): 512 + 8, 16B aligned
#define SQLD 20    // qlds row stride (floats): 16 + 4, 16B aligned
#define XLD  1032  // xlds row stride (floats): 1024 + 8, 16B aligned

typedef double v4df __attribute__((ext_vector_type(4)));

// ---------- top-4 helpers: total order = (value desc, index asc) ----------
__device__ __forceinline__ bool key_gt(float av, int ai, float bv, int bi) {
    return (av > bv) || (av == bv && ai < bi);
}

__device__ __forceinline__ void cmpswap(float& v0, int& i0, float& v1, int& i1) {
    bool sw = key_gt(v1, i1, v0, i0);
    float nv0 = sw ? v1 : v0, nv1 = sw ? v0 : v1;
    int   ni0 = sw ? i1 : i0, ni1 = sw ? i0 : i1;
    v0 = nv0; v1 = nv1; i0 = ni0; i1 = ni1;
}

// merge sorted-desc a[4] with sorted-desc b[4] -> top4 of union into a (bitonic)
__device__ __forceinline__ void merge4(float (&a)[4], int (&ai)[4],
                                       float b0, int j0, float b1, int j1,
                                       float b2, int j2, float b3, int j3) {
    if (!key_gt(a[0], ai[0], b3, j3)) { a[0] = b3; ai[0] = j3; }
    if (!key_gt(a[1], ai[1], b2, j2)) { a[1] = b2; ai[1] = j2; }
    if (!key_gt(a[2], ai[2], b1, j1)) { a[2] = b1; ai[2] = j1; }
    if (!key_gt(a[3], ai[3], b0, j0)) { a[3] = b0; ai[3] = j0; }
    cmpswap(a[0], ai[0], a[2], ai[2]);
    cmpswap(a[1], ai[1], a[3], ai[3]);
    cmpswap(a[0], ai[0], a[1], ai[1]);
    cmpswap(a[2], ai[2], a[3], ai[3]);
}

// insert candidate (v, idx) into sorted-desc top4; strict > keeps earlier index on ties
__device__ __forceinline__ void insert4(float (&tv)[4], int (&tix)[4], float v, int idx) {
    if (v > tv[3]) {
        bool g0 = v > tv[0], g1 = v > tv[1], g2 = v > tv[2];
        float n0 = g0 ? v : tv[0];
        int   m0 = g0 ? idx : tix[0];
        float n1 = g1 ? (g0 ? tv[0] : v) : tv[1];
        int   m1 = g1 ? (g0 ? tix[0] : idx) : tix[1];
        float n2 = g2 ? (g1 ? tv[1] : v) : tv[2];
        int   m2 = g2 ? (g1 ? tix[1] : idx) : tix[2];
        float n3 = g2 ? tv[2] : v;
        int   m3 = g2 ? tix[2] : idx;
        tv[0] = n0; tv[1] = n1; tv[2] = n2; tv[3] = n3;
        tix[0] = m0; tix[1] = m1; tix[2] = m2; tix[3] = m3;
    }
}

// ---------- probe body: f64 MFMA fragment layout, run by one 256-thr block ----------
// tab layout (ints): [0]=flag, [1..64]=am, [65..128]=ak, [129..192]=bk,
//                    [193..256]=bn, [257..512]=dm[lane][4], [513..768]=dn[lane][4]
__device__ void run_probe(int tid, int* __restrict__ tab)
{
    __shared__ double Aref[16][4];
    __shared__ double Bref[4][16];
    __shared__ double Dref[16][16];

    const int lane = tid;   // only tid<64 used for lane-specific work
    if (tid < 64) {
        const int m = lane & 15, k = lane >> 4;
        Aref[m][k] = (double)(1 + m * 4 + k);     // distinct, asymmetric
        Bref[k][m] = (double)(1 + k * 16 + m);
    }
    __syncthreads();
    {   // 256 threads: one D element each
        const int e = tid;
        const int m = e >> 4, n = e & 15;
        double s = 0.0;
        for (int k = 0; k < 4; ++k) s += Aref[m][k] * Bref[k][n];
        Dref[m][n] = s;   // exact integer-valued f64
    }
    __syncthreads();

    if (tid >= 64) return;   // wave 0 does the hypothesis search

    int found = -1;
    for (int h = 0; h < 16; ++h) {
        if (found >= 0) break;
        const int fa = h & 1, fb = (h >> 1) & 1, fd = h >> 2;
        const int am = fa ? (lane >> 2) : (lane & 15);
        const int ak = fa ? (lane & 3)  : (lane >> 4);
        const int bn = fb ? (lane >> 2) : (lane & 15);
        const int bk = fb ? (lane & 3)  : (lane >> 4);
        v4df c = {0.0, 0.0, 0.0, 0.0};
        c = __builtin_amdgcn_mfma_f64_16x16x4f64(Aref[am][ak], Bref[bk][bn], c, 0, 0, 0);
        bool ok = true;
        #pragma unroll
        for (int i = 0; i < 4; ++i) {
            int dm, dn;
            if (fd == 0)      { dm = 4 * (lane >> 4) + i; dn = lane & 15; }
            else if (fd == 1) { dn = 4 * (lane >> 4) + i; dm = lane & 15; }
            else if (fd == 2) { dm = (lane >> 4) + 4 * i; dn = lane & 15; }
            else              { dn = (lane >> 4) + 4 * i; dm = lane & 15; }
            if (c[i] != Dref[dm][dn]) ok = false;
        }
        if (__all(ok)) found = h;
    }

    const int fa = (found >= 0) ? (found & 1) : 0;
    const int fb = (found >= 0) ? ((found >> 1) & 1) : 0;
    const int fd = (found >= 0) ? (found >> 2) : 0;
    tab[1   + lane] = fa ? (lane >> 2) : (lane & 15);
    tab[65  + lane] = fa ? (lane & 3)  : (lane >> 4);
    tab[129 + lane] = fb ? (lane & 3)  : (lane >> 4);
    tab[193 + lane] = fb ? (lane >> 2) : (lane & 15);
    #pragma unroll
    for (int i = 0; i < 4; ++i) {
        int dm, dn;
        if (fd == 0)      { dm = 4 * (lane >> 4) + i; dn = lane & 15; }
        else if (fd == 1) { dn = 4 * (lane >> 4) + i; dm = lane & 15; }
        else if (fd == 2) { dm = (lane >> 4) + 4 * i; dn = lane & 15; }
        else              { dn = (lane >> 4) + 4 * i; dm = lane & 15; }
        tab[257 + lane * 4 + i] = dm;
        tab[513 + lane * 4 + i] = dn;
    }
    if (lane == 0) tab[0] = found;
}

// ---------- Phase 1: W convert (all blocks) + probe (block 0) ----------
__global__ __launch_bounds__(256) void wprep_probe(
    const float* __restrict__ Wq, const float* __restrict__ Wk,
    double* __restrict__ Wdt, int* __restrict__ tab)
{
    const int tid = threadIdx.x;
    const int idx = blockIdx.x * 256 + tid;   // 65536 total
    const int o = idx & 63;
    const int d = idx >> 6;
    float v = (o < 32) ? Wq[(size_t)o * D_MODEL + d]
                       : Wk[(size_t)(o - 32) * D_MODEL + d];
    Wdt[(size_t)d * 64 + o] = (double)v;

    if (blockIdx.x == 0) run_probe(tid, tab); // full-block barriers inside
}

// ---------- Phase 2: projection via f64 MFMA, d-split wave pairs ----------
// grid 512 (= 8192 rows / 16), block 512 (8 waves). Wave pair (og, half):
// og = wav>>1 owns out-tile og*16; half = wav&1 owns d in [half*512, half*512+512).
// x staged once (16 rows x 1024 d, 66 KB); f64 combine low+high fixed order.
__global__ __launch_bounds__(512) void proj_mfma(
    const float* __restrict__ x, const double* __restrict__ Wdt,
    const float* __restrict__ bq, const float* __restrict__ bk_,
    const int* __restrict__ tab,
    float* __restrict__ Qt, float* __restrict__ Kt)
{
    __shared__ float  xlds[16 * XLD];     // 66048 B
    __shared__ double comb[4][64][4];     // 8192 B

    const int tid  = threadIdx.x;
    const int lane = tid & 63;
    const int wav  = tid >> 6;                                      // 0..7
    const int og   = __builtin_amdgcn_readfirstlane(wav >> 1);      // 0..3
    const int half = __builtin_amdgcn_readfirstlane(wav & 1);       // 0..1
    const int row0 = blockIdx.x * 16;
    const int dbase = half * 512;

    const int flag = tab[0];
    const int am  = tab[1   + lane];
    const int ak  = tab[65  + lane];
    const int bkk = tab[129 + lane];
    const int bn  = tab[193 + lane];

    const double* wcol = Wdt + og * 16;   // + d*64 + bn

    // stage x: 16 rows x 1024 d = 4096 float4, 8 per thread, coalesced
    #pragma unroll
    for (int j = 0; j < 8; ++j) {
        const int f  = j * 512 + tid;
        const int r  = f >> 8;            // 0..15
        const int c4 = f & 255;           // float4 within row
        float4 v = *reinterpret_cast<const float4*>(
            x + (size_t)(row0 + r) * D_MODEL + c4 * 4);
        *reinterpret_cast<float4*>(&xlds[r * XLD + c4 * 4]) = v;
    }
    __syncthreads();

    v4df acc = {0.0, 0.0, 0.0, 0.0};

    if (flag >= 0) {
        // 128 chained MFMAs over this half's 512 d (k ascending, deterministic)
        #pragma unroll 8
        for (int kk = 0; kk < 128; ++kk) {
            double a = (double)xlds[am * XLD + dbase + kk * 4 + ak];
            double b = wcol[(size_t)(dbase + kk * 4 + bkk) * 64 + bn];
            acc = __builtin_amdgcn_mfma_f64_16x16x4f64(a, b, acc, 0, 0, 0);
        }
    } else {
        // scalar f64 fallback: out n = lane&15, rows 4*(lane>>4)+i
        const int n  = lane & 15;
        const int r4 = (lane >> 4) * 4;
        for (int dd = 0; dd < 512; ++dd) {
            const int d = dbase + dd;
            double wv = wcol[(size_t)d * 64 + n];
            #pragma unroll
            for (int i = 0; i < 4; ++i)
                acc[i] = fma((double)xlds[(r4 + i) * XLD + d], wv, acc[i]);
        }
    }

    if (half == 1) {
        #pragma unroll
        for (int i = 0; i < 4; ++i) comb[og][lane][i] = acc[i];
    }
    __syncthreads();

    if (half == 0) {
        // total = low + high (fixed order -> deterministic), + bias, store
        #pragma unroll
        for (int i = 0; i < 4; ++i) {
            const double tot = acc[i] + comb[og][lane][i];
            const int dmv = tab[257 + lane * 4 + i];
            const int dnv = tab[513 + lane * 4 + i];
            const int out = og * 16 + dnv;
            const int row = row0 + dmv;
            const int bb  = row >> 11, t = row & 2047;
            const double bias = (out < 32) ? (double)bq[out] : (double)bk_[out - 32];
            const float v = (float)(tot + bias);
            if (out < 32) Qt[((size_t)bb * 32 + out) * T_SEQ + t] = v;
            else          Kt[((size_t)bb * 32 + (out - 32)) * T_SEQ + t] = v;
        }
    }
}

// ---------- Phase 3: sim + top-4 + gather, fully block-local ----------
// grid 512 = b(4) x ttile(128 x 16 rows); block 256 (4 waves).
// Each block computes ALL 2048 s for its 16 t-rows (4 K-stages of 512 s),
// so top-4 completes locally -> gather fused with only __syncthreads().
// No atomics, no device fences (round-1 lesson: cross-XCD fences serialized
// on L2 writeback and cost 150+ us).
// LDS: klds 32x520 = 66.5 KB (+qlds 2.5 KB) -> 2 blocks/CU = 8 waves/CU.
// Micro-tile 4t x 8s per thread; t-group = tid&3, s-group = tid>>2.
__global__ __launch_bounds__(256, 2) void sim_topk_gather(
    const float* __restrict__ x,
    const float* __restrict__ Qt, const float* __restrict__ Kt,
    float* __restrict__ out)
{
    __shared__ float klds[32 * SKLD];     // 66560 B
    __shared__ float qlds[32 * SQLD];     // 2560 B
    // aliases into klds, used only after the FMA stages (barrier-protected)
    float (*cV)[16][4] = reinterpret_cast<float(*)[16][4]>(klds);          // 1024 B
    int   (*cI)[16][4] = reinterpret_cast<int(*)[16][4]>(klds + 256);      // 1024 B
    int   (*topIdx)[4] = reinterpret_cast<int(*)[4]>(klds + 512);          // 256 B

    const int tid  = threadIdx.x;
    const int lane = tid & 63;
    const int wav  = tid >> 6;            // 0..3
    const int tt   = blockIdx.x & 127;
    const int b    = blockIdx.x >> 7;
    const int tblk = tt * 16;

    const float* QtB = Qt + (size_t)b * 32 * T_SEQ;
    const float* KtB = Kt + (size_t)b * 32 * T_SEQ;

    // stage Q^T tile: 32 i x 16 t (128 float4s, threads 0..127)
    if (tid < 128) {
        const int i  = tid >> 2;
        const int t4 = (tid & 3) * 4;
        float4 v = *reinterpret_cast<const float4*>(QtB + (size_t)i * T_SEQ + tblk + t4);
        *reinterpret_cast<float4*>(&qlds[i * SQLD + t4]) = v;
    }

    const int t0 = (tid & 3) * 4;         // 4 t-groups x 4 rows = 16 rows
    const int s0 = (tid >> 2) * 8;        // 64 s-groups x 8 = 512 s per stage

    float tv[4][4]; int tix[4][4];
    #pragma unroll
    for (int r = 0; r < 4; ++r)
        #pragma unroll
        for (int j = 0; j < 4; ++j) { tv[r][j] = -INFINITY; tix[r][j] = 0x7fffffff; }

    for (int st = 0; st < 4; ++st) {
        __syncthreads();   // covers qlds at st==0, prev klds consumption after
        // stage K^T tile: 32 i x 512 s (4096 float4s, 16/thread), coalesced
        #pragma unroll
        for (int j = 0; j < 16; ++j) {
            const int f  = tid + j * 256;     // float4 index over [32][128]
            const int ki = f >> 7;
            const int ks = (f & 127) * 4;
            float4 v = *reinterpret_cast<const float4*>(
                KtB + (size_t)ki * T_SEQ + st * 512 + ks);
            *reinterpret_cast<float4*>(&klds[ki * SKLD + ks]) = v;
        }
        __syncthreads();

        float acc[4][8];
        #pragma unroll
        for (int r = 0; r < 4; ++r)
            #pragma unroll
            for (int c = 0; c < 8; ++c) acc[r][c] = 0.f;

        #pragma unroll 4
        for (int i = 0; i < 32; ++i) {
            float4 qv  = *reinterpret_cast<const float4*>(&qlds[i * SQLD + t0]);
            float4 kv0 = *reinterpret_cast<const float4*>(&klds[i * SKLD + s0]);
            float4 kv1 = *reinterpret_cast<const float4*>(&klds[i * SKLD + s0 + 4]);
            const float qa[4] = {qv.x, qv.y, qv.z, qv.w};
            const float ka[8] = {kv0.x, kv0.y, kv0.z, kv0.w, kv1.x, kv1.y, kv1.z, kv1.w};
            #pragma unroll
            for (int r = 0; r < 4; ++r)
                #pragma unroll
                for (int c = 0; c < 8; ++c)
                    acc[r][c] = fmaf(qa[r], ka[c], acc[r][c]);
        }

        const int sbase = st * 512 + s0;
        #pragma unroll
        for (int c = 0; c < 8; ++c)
            #pragma unroll
            for (int r = 0; r < 4; ++r)
                insert4(tv[r], tix[r], acc[r][c], sbase + c);
    }

    // in-wave butterfly: masks 4..32 preserve t-group (lane&3)
    #pragma unroll
    for (int m = 4; m <= 32; m <<= 1) {
        #pragma unroll
        for (int r = 0; r < 4; ++r) {
            float b0 = __shfl_xor(tv[r][0], m, 64);
            float b1 = __shfl_xor(tv[r][1], m, 64);
            float b2 = __shfl_xor(tv[r][2], m, 64);
            float b3 = __shfl_xor(tv[r][3], m, 64);
            int   j0 = __shfl_xor(tix[r][0], m, 64);
            int   j1 = __shfl_xor(tix[r][1], m, 64);
            int   j2 = __shfl_xor(tix[r][2], m, 64);
            int   j3 = __shfl_xor(tix[r][3], m, 64);
            merge4(tv[r], tix[r], b0, j0, b1, j1, b2, j2, b3, j3);
        }
    }

    __syncthreads();   // klds dead everywhere before aliased cV/cI writes

    if (lane < 4) {    // lane == t-group; rows lane*4+r
        #pragma unroll
        for (int r = 0; r < 4; ++r)
            #pragma unroll
            for (int j = 0; j < 4; ++j) {
                cV[wav][lane * 4 + r][j] = tv[r][j];
                cI[wav][lane * 4 + r][j] = tix[r][j];
            }
    }
    __syncthreads();

    // cross-wave merge (4 waves) -> final top-4 per row (16 rows)
    if (tid < 16) {
        float mv[4]; int mi[4];
        #pragma unroll
        for (int j = 0; j < 4; ++j) { mv[j] = cV[0][tid][j]; mi[j] = cI[0][tid][j]; }
        #pragma unroll
        for (int w = 1; w < 4; ++w)
            merge4(mv, mi,
                   cV[w][tid][0], cI[w][tid][0],
                   cV[w][tid][1], cI[w][tid][1],
                   cV[w][tid][2], cI[w][tid][2],
                   cV[w][tid][3], cI[w][tid][3]);
        #pragma unroll
        for (int j = 0; j < 4; ++j) topIdx[tid][j] = mi[j];
    }
    __syncthreads();

    // gather + mean for this block's 16 rows; 256 threads cover the 1024-float row
    const float* xb = x + (size_t)b * T_SEQ * D_MODEL;
    float* ob = out + ((size_t)b * T_SEQ + tblk) * D_MODEL;
    #pragma unroll 4
    for (int r = 0; r < 16; ++r) {
        const int i0 = topIdx[r][0], i1 = topIdx[r][1], i2 = topIdx[r][2], i3 = topIdx[r][3];
        float4 a0 = *(reinterpret_cast<const float4*>(xb + (size_t)i0 * D_MODEL) + tid);
        float4 a1 = *(reinterpret_cast<const float4*>(xb + (size_t)i1 * D_MODEL) + tid);
        float4 a2 = *(reinterpret_cast<const float4*>(xb + (size_t)i2 * D_MODEL) + tid);
        float4 a3 = *(reinterpret_cast<const float4*>(xb + (size_t)i3 * D_MODEL) + tid);
        float4 o;
        o.x = (a0.x + a1.x + a2.x + a3.x) * 0.25f;
        o.y = (a0.y + a1.y + a2.y + a3.y) * 0.25f;
        o.z = (a0.z + a1.z + a2.z + a3.z) * 0.25f;
        o.w = (a0.w + a1.w + a2.w + a3.w) * 0.25f;
        *(reinterpret_cast<float4*>(ob + (size_t)r * D_MODEL) + tid) = o;
    }
}

extern "C" void kernel_launch(void* const* d_in, const int* in_sizes, int n_in,
                              void* d_out, int out_size, void* d_ws, size_t ws_size,
                              hipStream_t stream) {
    const float* x  = (const float*)d_in[0];
    const float* Wq = (const float*)d_in[1];
    const float* bq = (const float*)d_in[2];
    const float* Wk = (const float*)d_in[3];
    const float* bk = (const float*)d_in[4];
    float* out = (float*)d_out;

    // ws layout: [tab 4KB][Wdt 512KB][Qt 1MB][Kt 1MB]
    char* wsb = (char*)d_ws;
    int*    tab  = (int*)wsb;                                            // 4 KB reserved
    double* Wdt  = (double*)(wsb + 4096);                                // 512 KB
    float*  Qt   = (float*)(wsb + 4096 + (size_t)D_MODEL * NOUT * 8);    // 1 MB
    float*  Kt   = Qt + (size_t)NBATCH * 32 * T_SEQ;                     // 1 MB

    wprep_probe<<<dim3(256), dim3(256), 0, stream>>>(Wq, Wk, Wdt, tab);
    proj_mfma<<<dim3(NROWS / 16), dim3(512), 0, stream>>>(x, Wdt, bq, bk, tab, Qt, Kt);
    sim_topk_gather<<<dim3(512), dim3(256), 0, stream>>>(x, Qt, Kt, out);
}

// Round 3
// 160.033 us; speedup vs baseline: 1.8316x; 1.0139x over previous
//
#include <hip/hip_runtime.h>
#include <math.h>

#define D_MODEL 1024
#define T_SEQ   2048
#define NBATCH  4
#define NROWS   (NBATCH * T_SEQ)          // 8192
#define NOUT    64                        // 32 q + 32 k

#define XLD  1036  // xlds row stride (floats): 1024 + 12; 1036 mod 32 = 12 ->
                   // a-operand ds_read_b32 lane pattern (16 rows x 4 ak) is 2-way = free
                   // (old 1032 ≡ 8 mod 32 was a 4-way conflict on every MFMA's a-read)

typedef double v4df __attribute__((ext_vector_type(4)));

// ---------- top-4 helpers: total order = (value desc, index asc) ----------
__device__ __forceinline__ bool key_gt(float av, int ai, float bv, int bi) {
    return (av > bv) || (av == bv && ai < bi);
}

__device__ __forceinline__ void cmpswap(float& v0, int& i0, float& v1, int& i1) {
    bool sw = key_gt(v1, i1, v0, i0);
    float nv0 = sw ? v1 : v0, nv1 = sw ? v0 : v1;
    int   ni0 = sw ? i1 : i0, ni1 = sw ? i0 : i1;
    v0 = nv0; v1 = nv1; i0 = ni0; i1 = ni1;
}

// merge sorted-desc a[4] with sorted-desc b[4] -> top4 of union into a (bitonic)
__device__ __forceinline__ void merge4(float (&a)[4], int (&ai)[4],
                                       float b0, int j0, float b1, int j1,
                                       float b2, int j2, float b3, int j3) {
    if (!key_gt(a[0], ai[0], b3, j3)) { a[0] = b3; ai[0] = j3; }
    if (!key_gt(a[1], ai[1], b2, j2)) { a[1] = b2; ai[1] = j2; }
    if (!key_gt(a[2], ai[2], b1, j1)) { a[2] = b1; ai[2] = j1; }
    if (!key_gt(a[3], ai[3], b0, j0)) { a[3] = b0; ai[3] = j0; }
    cmpswap(a[0], ai[0], a[2], ai[2]);
    cmpswap(a[1], ai[1], a[3], ai[3]);
    cmpswap(a[0], ai[0], a[1], ai[1]);
    cmpswap(a[2], ai[2], a[3], ai[3]);
}

// insert candidate (v, idx) into sorted-desc top4; strict > keeps earlier index on ties
__device__ __forceinline__ void insert4(float (&tv)[4], int (&tix)[4], float v, int idx) {
    if (v > tv[3]) {
        bool g0 = v > tv[0], g1 = v > tv[1], g2 = v > tv[2];
        float n0 = g0 ? v : tv[0];
        int   m0 = g0 ? idx : tix[0];
        float n1 = g1 ? (g0 ? tv[0] : v) : tv[1];
        int   m1 = g1 ? (g0 ? tix[0] : idx) : tix[1];
        float n2 = g2 ? (g1 ? tv[1] : v) : tv[2];
        int   m2 = g2 ? (g1 ? tix[1] : idx) : tix[2];
        float n3 = g2 ? tv[2] : v;
        int   m3 = g2 ? tix[2] : idx;
        tv[0] = n0; tv[1] = n1; tv[2] = n2; tv[3] = n3;
        tix[0] = m0; tix[1] = m1; tix[2] = m2; tix[3] = m3;
    }
}

// ---------- probe body: f64 MFMA fragment layout, run by one 256-thr block ----------
// tab layout (ints): [0]=flag, [1..64]=am, [65..128]=ak, [129..192]=bk,
//                    [193..256]=bn, [257..512]=dm[lane][4], [513..768]=dn[lane][4]
__device__ void run_probe(int tid, int* __restrict__ tab)
{
    __shared__ double Aref[16][4];
    __shared__ double Bref[4][16];
    __shared__ double Dref[16][16];

    const int lane = tid;   // only tid<64 used for lane-specific work
    if (tid < 64) {
        const int m = lane & 15, k = lane >> 4;
        Aref[m][k] = (double)(1 + m * 4 + k);     // distinct, asymmetric
        Bref[k][m] = (double)(1 + k * 16 + m);
    }
    __syncthreads();
    {   // 256 threads: one D element each
        const int e = tid;
        const int m = e >> 4, n = e & 15;
        double s = 0.0;
        for (int k = 0; k < 4; ++k) s += Aref[m][k] * Bref[k][n];
        Dref[m][n] = s;   // exact integer-valued f64
    }
    __syncthreads();

    if (tid >= 64) return;   // wave 0 does the hypothesis search

    int found = -1;
    for (int h = 0; h < 16; ++h) {
        if (found >= 0) break;
        const int fa = h & 1, fb = (h >> 1) & 1, fd = h >> 2;
        const int am = fa ? (lane >> 2) : (lane & 15);
        const int ak = fa ? (lane & 3)  : (lane >> 4);
        const int bn = fb ? (lane >> 2) : (lane & 15);
        const int bk = fb ? (lane & 3)  : (lane >> 4);
        v4df c = {0.0, 0.0, 0.0, 0.0};
        c = __builtin_amdgcn_mfma_f64_16x16x4f64(Aref[am][ak], Bref[bk][bn], c, 0, 0, 0);
        bool ok = true;
        #pragma unroll
        for (int i = 0; i < 4; ++i) {
            int dm, dn;
            if (fd == 0)      { dm = 4 * (lane >> 4) + i; dn = lane & 15; }
            else if (fd == 1) { dn = 4 * (lane >> 4) + i; dm = lane & 15; }
            else if (fd == 2) { dm = (lane >> 4) + 4 * i; dn = lane & 15; }
            else              { dn = (lane >> 4) + 4 * i; dm = lane & 15; }
            if (c[i] != Dref[dm][dn]) ok = false;
        }
        if (__all(ok)) found = h;
    }

    const int fa = (found >= 0) ? (found & 1) : 0;
    const int fb = (found >= 0) ? ((found >> 1) & 1) : 0;
    const int fd = (found >= 0) ? (found >> 2) : 0;
    tab[1   + lane] = fa ? (lane >> 2) : (lane & 15);
    tab[65  + lane] = fa ? (lane & 3)  : (lane >> 4);
    tab[129 + lane] = fb ? (lane & 3)  : (lane >> 4);
    tab[193 + lane] = fb ? (lane >> 2) : (lane & 15);
    #pragma unroll
    for (int i = 0; i < 4; ++i) {
        int dm, dn;
        if (fd == 0)      { dm = 4 * (lane >> 4) + i; dn = lane & 15; }
        else if (fd == 1) { dn = 4 * (lane >> 4) + i; dm = lane & 15; }
        else if (fd == 2) { dm = (lane >> 4) + 4 * i; dn = lane & 15; }
        else              { dn = (lane >> 4) + 4 * i; dm = lane & 15; }
        tab[257 + lane * 4 + i] = dm;
        tab[513 + lane * 4 + i] = dn;
    }
    if (lane == 0) tab[0] = found;
}

// ---------- Phase 1: W convert (all blocks) + probe (block 0) ----------
__global__ __launch_bounds__(256) void wprep_probe(
    const float* __restrict__ Wq, const float* __restrict__ Wk,
    double* __restrict__ Wdt, int* __restrict__ tab)
{
    const int tid = threadIdx.x;
    const int idx = blockIdx.x * 256 + tid;   // 65536 total
    const int o = idx & 63;
    const int d = idx >> 6;
    float v = (o < 32) ? Wq[(size_t)o * D_MODEL + d]
                       : Wk[(size_t)(o - 32) * D_MODEL + d];
    Wdt[(size_t)d * 64 + o] = (double)v;

    if (blockIdx.x == 0) run_probe(tid, tab); // full-block barriers inside
}

// ---------- Phase 2: projection via f64 MFMA, d-split wave pairs ----------
// grid 512 (= 8192 rows / 16), block 512 (8 waves). Wave pair (og, half):
// og = wav>>1 owns out-tile og*16; half = wav&1 owns d in [half*512, half*512+512).
// x staged once (16 rows x 1024 d); f64 combine low+high fixed order.
__global__ __launch_bounds__(512) void proj_mfma(
    const float* __restrict__ x, const double* __restrict__ Wdt,
    const float* __restrict__ bq, const float* __restrict__ bk_,
    const int* __restrict__ tab,
    float* __restrict__ Qt, float* __restrict__ Kt)
{
    __shared__ float  xlds[16 * XLD];     // 66304 B
    __shared__ double comb[4][64][4];     // 8192 B

    const int tid  = threadIdx.x;
    const int lane = tid & 63;
    const int wav  = tid >> 6;                                      // 0..7
    const int og   = __builtin_amdgcn_readfirstlane(wav >> 1);      // 0..3
    const int half = __builtin_amdgcn_readfirstlane(wav & 1);       // 0..1
    const int row0 = blockIdx.x * 16;
    const int dbase = half * 512;

    const int flag = tab[0];
    const int am  = tab[1   + lane];
    const int ak  = tab[65  + lane];
    const int bkk = tab[129 + lane];
    const int bn  = tab[193 + lane];

    const double* wcol = Wdt + og * 16;   // + d*64 + bn

    // stage x: 16 rows x 1024 d = 4096 float4, 8 per thread, coalesced
    #pragma unroll
    for (int j = 0; j < 8; ++j) {
        const int f  = j * 512 + tid;
        const int r  = f >> 8;            // 0..15
        const int c4 = f & 255;           // float4 within row
        float4 v = *reinterpret_cast<const float4*>(
            x + (size_t)(row0 + r) * D_MODEL + c4 * 4);
        *reinterpret_cast<float4*>(&xlds[r * XLD + c4 * 4]) = v;
    }
    __syncthreads();

    v4df acc = {0.0, 0.0, 0.0, 0.0};

    if (flag >= 0) {
        // 128 chained MFMAs over this half's 512 d (k ascending, deterministic)
        #pragma unroll 8
        for (int kk = 0; kk < 128; ++kk) {
            double a = (double)xlds[am * XLD + dbase + kk * 4 + ak];
            double b = wcol[(size_t)(dbase + kk * 4 + bkk) * 64 + bn];
            acc = __builtin_amdgcn_mfma_f64_16x16x4f64(a, b, acc, 0, 0, 0);
        }
    } else {
        // scalar f64 fallback: out n = lane&15, rows 4*(lane>>4)+i
        const int n  = lane & 15;
        const int r4 = (lane >> 4) * 4;
        for (int dd = 0; dd < 512; ++dd) {
            const int d = dbase + dd;
            double wv = wcol[(size_t)d * 64 + n];
            #pragma unroll
            for (int i = 0; i < 4; ++i)
                acc[i] = fma((double)xlds[(r4 + i) * XLD + d], wv, acc[i]);
        }
    }

    if (half == 1) {
        #pragma unroll
        for (int i = 0; i < 4; ++i) comb[og][lane][i] = acc[i];
    }
    __syncthreads();

    if (half == 0) {
        // total = low + high (fixed order -> deterministic), + bias, store
        #pragma unroll
        for (int i = 0; i < 4; ++i) {
            const double tot = acc[i] + comb[og][lane][i];
            const int dmv = tab[257 + lane * 4 + i];
            const int dnv = tab[513 + lane * 4 + i];
            const int out = og * 16 + dnv;
            const int row = row0 + dmv;
            const int bb  = row >> 11, t = row & 2047;
            const double bias = (out < 32) ? (double)bq[out] : (double)bk_[out - 32];
            const float v = (float)(tot + bias);
            if (out < 32) Qt[((size_t)bb * 32 + out) * T_SEQ + t] = v;
            else          Kt[((size_t)bb * 32 + (out - 32)) * T_SEQ + t] = v;
        }
    }
}

// ---------- Phase 3: sim + top-4 + gather, L2-direct (no K staging) ----------
// Round-2 lesson: LDS-staging L2-resident Kt (256 KB/batch) cost 66 KB LDS ->
// 8 waves/CU and duplicated staging; kernel was latency-bound at VALUBusy 40%.
// Now: grid 1024 = b(4) x ttile(256 x 8 rows); block 256 (4 waves), LDS 2.2 KB
// -> 4 blocks/CU = 16 waves/CU, spare blocks overlap gather tails.
// Thread (tg = tid&1, sg = tid>>1): micro-tile 4t x 8s, k read straight from L2
// (lane pairs coalesce to 1 KB/instr), q via same-address broadcast load.
// Kt re-read: 256 KB x 1024 blocks = 256 MB L2 traffic ~= 7.4 us at 34.5 TB/s.
// FMA order (i ascending) identical to prior rounds -> bit-identical sims.
__global__ __launch_bounds__(256, 4) void sim_topk_gather(
    const float* __restrict__ x,
    const float* __restrict__ Qt, const float* __restrict__ Kt,
    float* __restrict__ out)
{
    __shared__ float cV[4][8][4];
    __shared__ int   cI[4][8][4];
    __shared__ int   topIdx[8][4];

    const int tid  = threadIdx.x;
    const int lane = tid & 63;
    const int wav  = tid >> 6;            // 0..3
    const int tt   = blockIdx.x & 255;
    const int b    = blockIdx.x >> 8;
    const int tblk = tt * 8;
    const int tg   = tid & 1;             // 2 t-groups x 4 rows = 8 rows
    const int sg   = tid >> 1;            // 128 s-groups x 8 s (x2 sweeps) = 2048 s

    const float* QtB = Qt + (size_t)b * 32 * T_SEQ;
    const float* KtB = Kt + (size_t)b * 32 * T_SEQ;
    const int trow0 = tblk + tg * 4;

    float tv[4][4]; int tix[4][4];
    #pragma unroll
    for (int r = 0; r < 4; ++r)
        #pragma unroll
        for (int j = 0; j < 4; ++j) { tv[r][j] = -INFINITY; tix[r][j] = 0x7fffffff; }

    #pragma unroll
    for (int sweep = 0; sweep < 2; ++sweep) {
        const int s0 = sweep * 1024 + sg * 8;

        float acc[4][8];
        #pragma unroll
        for (int r = 0; r < 4; ++r)
            #pragma unroll
            for (int c = 0; c < 8; ++c) acc[r][c] = 0.f;

        #pragma unroll 4
        for (int i = 0; i < 32; ++i) {
            float4 qv  = *reinterpret_cast<const float4*>(QtB + (size_t)i * T_SEQ + trow0);
            float4 kv0 = *reinterpret_cast<const float4*>(KtB + (size_t)i * T_SEQ + s0);
            float4 kv1 = *reinterpret_cast<const float4*>(KtB + (size_t)i * T_SEQ + s0 + 4);
            const float qa[4] = {qv.x, qv.y, qv.z, qv.w};
            const float ka[8] = {kv0.x, kv0.y, kv0.z, kv0.w, kv1.x, kv1.y, kv1.z, kv1.w};
            #pragma unroll
            for (int r = 0; r < 4; ++r)
                #pragma unroll
                for (int c = 0; c < 8; ++c)
                    acc[r][c] = fmaf(qa[r], ka[c], acc[r][c]);
        }

        #pragma unroll
        for (int c = 0; c < 8; ++c)
            #pragma unroll
            for (int r = 0; r < 4; ++r)
                insert4(tv[r], tix[r], acc[r][c], s0 + c);
    }

    // in-wave butterfly: masks 2..32 preserve t-group (lane&1)
    #pragma unroll
    for (int m = 2; m <= 32; m <<= 1) {
        #pragma unroll
        for (int r = 0; r < 4; ++r) {
            float b0 = __shfl_xor(tv[r][0], m, 64);
            float b1 = __shfl_xor(tv[r][1], m, 64);
            float b2 = __shfl_xor(tv[r][2], m, 64);
            float b3 = __shfl_xor(tv[r][3], m, 64);
            int   j0 = __shfl_xor(tix[r][0], m, 64);
            int   j1 = __shfl_xor(tix[r][1], m, 64);
            int   j2 = __shfl_xor(tix[r][2], m, 64);
            int   j3 = __shfl_xor(tix[r][3], m, 64);
            merge4(tv[r], tix[r], b0, j0, b1, j1, b2, j2, b3, j3);
        }
    }

    if (lane < 2) {    // lane == tg; rows lane*4+r
        #pragma unroll
        for (int r = 0; r < 4; ++r)
            #pragma unroll
            for (int j = 0; j < 4; ++j) {
                cV[wav][lane * 4 + r][j] = tv[r][j];
                cI[wav][lane * 4 + r][j] = tix[r][j];
            }
    }
    __syncthreads();

    // cross-wave merge (4 waves) -> final top-4 per row (8 rows)
    if (tid < 8) {
        float mv[4]; int mi[4];
        #pragma unroll
        for (int j = 0; j < 4; ++j) { mv[j] = cV[0][tid][j]; mi[j] = cI[0][tid][j]; }
        #pragma unroll
        for (int w = 1; w < 4; ++w)
            merge4(mv, mi,
                   cV[w][tid][0], cI[w][tid][0],
                   cV[w][tid][1], cI[w][tid][1],
                   cV[w][tid][2], cI[w][tid][2],
                   cV[w][tid][3], cI[w][tid][3]);
        #pragma unroll
        for (int j = 0; j < 4; ++j) topIdx[tid][j] = mi[j];
    }
    __syncthreads();

    // gather + mean for this block's 8 rows; 256 threads cover the 1024-float row
    const float* xb = x + (size_t)b * T_SEQ * D_MODEL;
    float* ob = out + ((size_t)b * T_SEQ + tblk) * D_MODEL;
    #pragma unroll 4
    for (int r = 0; r < 8; ++r) {
        const int i0 = topIdx[r][0], i1 = topIdx[r][1], i2 = topIdx[r][2], i3 = topIdx[r][3];
        float4 a0 = *(reinterpret_cast<const float4*>(xb + (size_t)i0 * D_MODEL) + tid);
        float4 a1 = *(reinterpret_cast<const float4*>(xb + (size_t)i1 * D_MODEL) + tid);
        float4 a2 = *(reinterpret_cast<const float4*>(xb + (size_t)i2 * D_MODEL) + tid);
        float4 a3 = *(reinterpret_cast<const float4*>(xb + (size_t)i3 * D_MODEL) + tid);
        float4 o;
        o.x = (a0.x + a1.x + a2.x + a3.x) * 0.25f;
        o.y = (a0.y + a1.y + a2.y + a3.y) * 0.25f;
        o.z = (a0.z + a1.z + a2.z + a3.z) * 0.25f;
        o.w = (a0.w + a1.w + a2.w + a3.w) * 0.25f;
        *(reinterpret_cast<float4*>(ob + (size_t)r * D_MODEL) + tid) = o;
    }
}

extern "C" void kernel_launch(void* const* d_in, const int* in_sizes, int n_in,
                              void* d_out, int out_size, void* d_ws, size_t ws_size,
                              hipStream_t stream) {
    const float* x  = (const float*)d_in[0];
    const float* Wq = (const float*)d_in[1];
    const float* bq = (const float*)d_in[2];
    const float* Wk = (const float*)d_in[3];
    const float* bk = (const float*)d_in[4];
    float* out = (float*)d_out;

    // ws layout: [tab 4KB][Wdt 512KB][Qt 1MB][Kt 1MB]
    char* wsb = (char*)d_ws;
    int*    tab  = (int*)wsb;                                            // 4 KB reserved
    double* Wdt  = (double*)(wsb + 4096);                                // 512 KB
    float*  Qt   = (float*)(wsb + 4096 + (size_t)D_MODEL * NOUT * 8);    // 1 MB
    float*  Kt   = Qt + (size_t)NBATCH * 32 * T_SEQ;                     // 1 MB

    wprep_probe<<<dim3(256), dim3(256), 0, stream>>>(Wq, Wk, Wdt, tab);
    proj_mfma<<<dim3(NROWS / 16), dim3(512), 0, stream>>>(x, Wdt, bq, bk, tab, Qt, Kt);
    sim_topk_gather<<<dim3(1024), dim3(256), 0, stream>>>(x, Qt, Kt, out);
}